// Round 22
// baseline (104.007 us; speedup 1.0000x reference)
//
#include <hip/hip_runtime.h>
#include <hip/hip_bf16.h>

typedef __bf16 bf16_t;
typedef bf16_t bf16x8 __attribute__((ext_vector_type(8)));
typedef bf16_t bf16x4 __attribute__((ext_vector_type(4)));
typedef float f32x4 __attribute__((ext_vector_type(4)));
typedef float f32x16 __attribute__((ext_vector_type(16)));

#define EXP2C 0.1803368867f  // 0.125 * log2(e)
#define FEXP2(x) __builtin_amdgcn_exp2f(x)  // v_exp_f32 (base-2)

// async global->LDS, 16B per lane (dest must be wave-uniform base + lane*16)
__device__ __forceinline__ void gload16(const void* g, void* l) {
  __builtin_amdgcn_global_load_lds(
      (const __attribute__((address_space(1))) void*)g,
      (__attribute__((address_space(3))) void*)l, 16, 0, 0);
}

__device__ __forceinline__ unsigned pkbf(float lo, float hi) {
  unsigned short a = __builtin_bit_cast(unsigned short, (bf16_t)lo);
  unsigned short b = __builtin_bit_cast(unsigned short, (bf16_t)hi);
  return (unsigned)a | ((unsigned)b << 16);
}

// v_permlane32_swap_b32: swaps a.hi(lanes32-63) with b.lo(lanes0-31).
__device__ __forceinline__ void plswap(unsigned& a, unsigned& b) {
#if __has_builtin(__builtin_amdgcn_permlane32_swap)
  auto r = __builtin_amdgcn_permlane32_swap(a, b, false, false);
  a = r[0]; b = r[1];
#else
  asm("v_permlane32_swap_b32 %0, %1" : "+v"(a), "+v"(b));
#endif
}
__device__ __forceinline__ float xmax32(float x) {
  unsigned a = __builtin_bit_cast(unsigned, x), b = a;
  plswap(a, b);
  return fmaxf(__builtin_bit_cast(float, a), __builtin_bit_cast(float, b));
}
__device__ __forceinline__ float xsum32(float x) {
  unsigned a = __builtin_bit_cast(unsigned, x), b = a;
  plswap(a, b);
  return __builtin_bit_cast(float, a) + __builtin_bit_cast(float, b);
}

// ---------------------------------------------------------------------------
// fused prep: cvt x, cvt pred_kg, tcvt Wc/Wk/Wp
// ---------------------------------------------------------------------------
__global__ __launch_bounds__(256) void prep_kernel(
    const float* __restrict__ x, bf16_t* __restrict__ xb,
    const float* __restrict__ pkg, bf16_t* __restrict__ pkb,
    const float* __restrict__ Wc, bf16_t* __restrict__ Wct,
    const float* __restrict__ Wk, bf16_t* __restrict__ Wkt,
    const float* __restrict__ Wp, bf16_t* __restrict__ Wpt) {
  __shared__ float tile[32][33];
  const int bid = blockIdx.x, tid = threadIdx.x;
  if (bid < 5120) {  // vector convert
    int i = bid * 256 + tid;
    const float* src; bf16_t* dst;
    if (i < 1048576) { src = x; dst = xb; }
    else { i -= 1048576; src = pkg; dst = pkb; }
    float4 v = reinterpret_cast<const float4*>(src)[i];
    bf16x4 o = { (bf16_t)v.x, (bf16_t)v.y, (bf16_t)v.z, (bf16_t)v.w };
    reinterpret_cast<bf16x4*>(dst)[i] = o;
    return;
  }
  int r = bid - 5120;
  int xx = r % 192, ky = r / 192;
  const float* W; bf16_t* T; int N;
  if (xx < 96) { W = Wc; T = Wct; N = 3072; }
  else if (xx < 160) { W = Wk; T = Wkt; N = 2048; xx -= 96; }
  else { W = Wp; T = Wpt; N = 1024; xx -= 160; }
  const int K = 1024;
  int tx = tid & 31, ty = tid >> 5;
  int n0 = xx * 32, k0 = ky * 32;
#pragma unroll
  for (int i = 0; i < 4; ++i)
    tile[ty + i * 8][tx] = W[(size_t)(k0 + ty + i * 8) * N + n0 + tx];
  __syncthreads();
#pragma unroll
  for (int i = 0; i < 4; ++i)
    T[(size_t)(n0 + ty + i * 8) * K + k0 + tx] = (bf16_t)tile[tx][ty + i * 8];
}

#define GBAR() __builtin_amdgcn_s_barrier()
#define LGKM0() asm volatile("s_waitcnt lgkmcnt(0)" ::: "memory")

// ---------------------------------------------------------------------------
// 256x256 8-wave GEMM body with fused fragment-pack epilogue (R21-verified).
// ---------------------------------------------------------------------------
__device__ __forceinline__ void gemm256_body(
    char* smem, const bf16_t* __restrict__ A, const bf16_t* __restrict__ Bt,
    const float* __restrict__ bias, bf16_t* __restrict__ Cout, int N,
    int K, int bx, int by, int mode, bf16_t* __restrict__ fdst,
    int NT, int bfb, int h0, int t0) {
  const int tid = threadIdx.x;
  const int l = tid & 63, w = tid >> 6;
  const int lr = l & 15, lg = l >> 4;
  const int m0 = by * 256, n0 = bx * 256;
  const int wr = (w >> 2) * 128, wc = (w & 3) * 64;
  const int hA = w >> 2, hB = (w >> 1) & 1;

  const int sr = tid >> 3;
  const int scb = ((tid & 7) * 16) ^ ((sr & 7) << 4);
  const bf16_t* Ab = A + (size_t)m0 * K + (scb >> 1);
  const bf16_t* Bb = Bt + (size_t)n0 * K + (scb >> 1);
  const int nk = K >> 6;
  const int xr = (lr & 7) << 4;

  auto STAGE_A = [&](int t, int h) {
    const bf16_t* g = Ab + (size_t)(h * 128 + sr) * K + t * 64;
    char* d = smem + ((size_t)(t & 1) * 2 + h) * 16384 + tid * 16;
    gload16(g, d);
    gload16(g + (size_t)64 * K, d + 8192);
  };
  auto STAGE_B = [&](int t, int h) {
    const bf16_t* g = Bb + (size_t)(h * 128 + sr) * K + t * 64;
    char* d = smem + 65536 + ((size_t)(t & 1) * 2 + h) * 16384 + tid * 16;
    gload16(g, d);
    gload16(g + (size_t)64 * K, d + 8192);
  };

  f32x4 acc[8][4] = {};
  bf16x8 af[4][2], bf[2][2][2];

  STAGE_A(0, 0); STAGE_A(0, 1); STAGE_B(0, 0); STAGE_B(0, 1);
  asm volatile("s_waitcnt vmcnt(0)" ::: "memory");
  GBAR();

  for (int t = 0; t < nk; ++t) {
    const char* pA = smem + ((size_t)(t & 1) * 2 + hA) * 16384;
    const char* pB = smem + 65536 + ((size_t)(t & 1) * 2 + hB) * 16384;
    auto LDA = [&](int mf, int ks) {
      return *(const bf16x8*)(pA + (mf * 16 + lr) * 128 + ((ks * 64 + lg * 16) ^ xr));
    };
    auto LDB = [&](int nf, int ks) {
      return *(const bf16x8*)(pB + ((w & 1) * 64 + nf * 16 + lr) * 128 + ((ks * 64 + lg * 16) ^ xr));
    };
#pragma unroll
    for (int mf = 0; mf < 4; ++mf) { af[mf][0] = LDA(mf, 0); af[mf][1] = LDA(mf, 1); }
#pragma unroll
    for (int nf = 0; nf < 2; ++nf) { bf[0][nf][0] = LDB(nf, 0); bf[0][nf][1] = LDB(nf, 1); }
    if (t + 1 < nk) { STAGE_A(t + 1, 0); STAGE_B(t + 1, 0); }
    GBAR(); LGKM0();
    __builtin_amdgcn_s_setprio(1);
#pragma unroll
    for (int mf = 0; mf < 4; ++mf)
#pragma unroll
      for (int nf = 0; nf < 2; ++nf) {
        acc[mf][nf] = __builtin_amdgcn_mfma_f32_16x16x32_bf16(af[mf][0], bf[0][nf][0], acc[mf][nf], 0, 0, 0);
        acc[mf][nf] = __builtin_amdgcn_mfma_f32_16x16x32_bf16(af[mf][1], bf[0][nf][1], acc[mf][nf], 0, 0, 0);
      }
    __builtin_amdgcn_s_setprio(0);
    GBAR();
#pragma unroll
    for (int nf = 0; nf < 2; ++nf) { bf[1][nf][0] = LDB(2 + nf, 0); bf[1][nf][1] = LDB(2 + nf, 1); }
    if (t + 1 < nk) { STAGE_A(t + 1, 1); STAGE_B(t + 1, 1); }
    GBAR(); LGKM0();
    __builtin_amdgcn_s_setprio(1);
#pragma unroll
    for (int mf = 0; mf < 4; ++mf)
#pragma unroll
      for (int nf = 0; nf < 2; ++nf) {
        acc[mf][2 + nf] = __builtin_amdgcn_mfma_f32_16x16x32_bf16(af[mf][0], bf[1][nf][0], acc[mf][2 + nf], 0, 0, 0);
        acc[mf][2 + nf] = __builtin_amdgcn_mfma_f32_16x16x32_bf16(af[mf][1], bf[1][nf][1], acc[mf][2 + nf], 0, 0, 0);
      }
    __builtin_amdgcn_s_setprio(0);
    GBAR();
#pragma unroll
    for (int mf = 0; mf < 4; ++mf) { af[mf][0] = LDA(4 + mf, 0); af[mf][1] = LDA(4 + mf, 1); }
    GBAR(); LGKM0();
    __builtin_amdgcn_s_setprio(1);
#pragma unroll
    for (int mf = 0; mf < 4; ++mf)
#pragma unroll
      for (int nf = 0; nf < 2; ++nf) {
        acc[4 + mf][nf] = __builtin_amdgcn_mfma_f32_16x16x32_bf16(af[mf][0], bf[0][nf][0], acc[4 + mf][nf], 0, 0, 0);
        acc[4 + mf][nf] = __builtin_amdgcn_mfma_f32_16x16x32_bf16(af[mf][1], bf[0][nf][1], acc[4 + mf][nf], 0, 0, 0);
      }
    __builtin_amdgcn_s_setprio(0);
    GBAR();
    __builtin_amdgcn_s_setprio(1);
#pragma unroll
    for (int mf = 0; mf < 4; ++mf)
#pragma unroll
      for (int nf = 0; nf < 2; ++nf) {
        acc[4 + mf][2 + nf] = __builtin_amdgcn_mfma_f32_16x16x32_bf16(af[mf][0], bf[1][nf][0], acc[4 + mf][2 + nf], 0, 0, 0);
        acc[4 + mf][2 + nf] = __builtin_amdgcn_mfma_f32_16x16x32_bf16(af[mf][1], bf[1][nf][1], acc[4 + mf][2 + nf], 0, 0, 0);
      }
    __builtin_amdgcn_s_setprio(0);
    asm volatile("s_waitcnt vmcnt(0)" ::: "memory");
    GBAR();
  }

  if (mode == 0) {  // linear bf16 store
#pragma unroll
    for (int mf = 0; mf < 8; ++mf) {
#pragma unroll
      for (int nf = 0; nf < 4; ++nf) {
        int col = n0 + wc + nf * 16 + lr;
        float bb = bias[col];
        int rowb = m0 + wr + mf * 16 + lg * 4;
#pragma unroll
        for (int r = 0; r < 4; ++r) {
          float v = acc[mf][nf][r] + bb;
          Cout[(size_t)(rowb + r) * N + col] = (bf16_t)v;
        }
      }
    }
    return;
  }

  // ---- fragment epilogue: acc -> swizzled LDS bf16 [256][256] ----
#pragma unroll
  for (int mf = 0; mf < 8; ++mf) {
#pragma unroll
    for (int nf = 0; nf < 4; ++nf) {
      int lcol = wc + nf * 16 + lr;
      float bb = bias[n0 + lcol];
      int rowb = wr + mf * 16 + lg * 4;
#pragma unroll
      for (int r = 0; r < 4; ++r) {
        int lrow = rowb + r;
        *(bf16_t*)(smem + lrow * 512 + ((lcol * 2) ^ ((lrow & 7) << 4))) =
            (bf16_t)(acc[mf][nf][r] + bb);
      }
    }
  }
  __syncthreads();
  if (mode == 1) {
#pragma unroll
    for (int i = 0; i < 16; ++i) {
      int g = i * 512 + tid;
      int sub = g >> 8, c = g & 255;
      int ks = c >> 6, l2 = c & 63;
      int tt = sub >> 2, hc = sub & 3;
      int lrow = tt * 32 + (l2 & 31);
      int lcol = hc * 64 + ks * 16 + ((l2 >> 5) * 8);
      uint4 d = *(uint4*)(smem + lrow * 512 + ((lcol * 2) ^ ((lrow & 7) << 4)));
      size_t obase = ((size_t)(bfb + h0 + hc) * NT + (t0 + tt)) * 2048;
      *(uint4*)&fdst[obase + ks * 512 + (size_t)l2 * 8] = d;
    }
  } else {
#pragma unroll
    for (int i = 0; i < 16; ++i) {
      int g = i * 512 + tid;
      int sub = g >> 8, c = g & 255;
      int dd = c >> 6, l2 = c & 63;
      int mb = dd >> 1, ks = dd & 1;
      int tt = sub >> 2, hc = sub & 3;
      int kvr = ks * 16 + ((l2 >> 5) * 8);
      int lcolv = hc * 64 + mb * 32 + (l2 & 31);
      bf16_t tmp[8];
#pragma unroll
      for (int j = 0; j < 8; ++j) {
        int lrow = tt * 32 + kvr + j;
        tmp[j] = *(bf16_t*)(smem + lrow * 512 + ((lcolv * 2) ^ ((lrow & 7) << 4)));
      }
      size_t obase = ((size_t)(bfb + h0 + hc) * NT + (t0 + tt)) * 2048;
      *(bf16x8*)&fdst[obase + dd * 512 + (size_t)l2 * 8] = *(bf16x8*)tmp;
    }
  }
}

__global__ __launch_bounds__(512, 1) void gemm2_kernel(
    const bf16_t* __restrict__ A0, const bf16_t* __restrict__ B0,
    const float* __restrict__ bi0, bf16_t* __restrict__ C0,
    const bf16_t* __restrict__ A1, const bf16_t* __restrict__ B1,
    const float* __restrict__ bi1,
    bf16_t* __restrict__ kfs, bf16_t* __restrict__ vfs,
    bf16_t* __restrict__ kfc, bf16_t* __restrict__ vfc) {
  extern __shared__ char smem[];
  int bid = blockIdx.x;
  int wg = (bid & 7) * 28 + (bid >> 3);
  if (wg < 192) {
    int bx = wg % 12, by = wg / 12;
    int b = by >> 2, t0 = (by & 3) * 8;
    if (bx < 4)
      gemm256_body(smem, A0, B0, bi0, C0, 3072, 1024, bx, by, 0, nullptr, 0, 0, 0, 0);
    else if (bx < 8)
      gemm256_body(smem, A0, B0, bi0, nullptr, 3072, 1024, bx, by, 1, kfs, 32, b * 16, (bx - 4) * 4, t0);
    else
      gemm256_body(smem, A0, B0, bi0, nullptr, 3072, 1024, bx, by, 2, vfs, 32, b * 16, (bx - 8) * 4, t0);
  } else {
    int r = wg - 192;
    int bx = r % 8, by = r / 8;
    if (bx < 4)
      gemm256_body(smem, A1, B1, bi1, nullptr, 2048, 1024, bx, by, 1, kfc, 8, by * 16, bx * 4, 0);
    else
      gemm256_body(smem, A1, B1, bi1, nullptr, 2048, 1024, bx, by, 2, vfc, 8, by * 16, (bx - 4) * 4, 0);
  }
}

// ---------------------------------------------------------------------------
// 8-phase GEMM body 256x128 (R15-verified) — proj (256 blocks = all CUs)
// ---------------------------------------------------------------------------
#define MFMA2(mi, ni)                                                         \
  acc[mi][ni] = __builtin_amdgcn_mfma_f32_16x16x32_bf16(af[(mi) & 1][0], bf[ni][0], acc[mi][ni], 0, 0, 0); \
  acc[mi][ni] = __builtin_amdgcn_mfma_f32_16x16x32_bf16(af[(mi) & 1][1], bf[ni][1], acc[mi][ni], 0, 0, 0);
#define MFMA8(qm, qn)                                                         \
  MFMA2(2 * (qm) + 0, 2 * (qn) + 0) MFMA2(2 * (qm) + 0, 2 * (qn) + 1)         \
  MFMA2(2 * (qm) + 1, 2 * (qn) + 0) MFMA2(2 * (qm) + 1, 2 * (qn) + 1)

__device__ __forceinline__ void gemm8_body(
    char* smem, const bf16_t* __restrict__ A, const bf16_t* __restrict__ Bt,
    const float* __restrict__ bias, float* __restrict__ Cout,
    int N, int K, int bx, int by) {
  const int tid = threadIdx.x;
  const int l = tid & 63, w = tid >> 6;
  const int lr = l & 15, lg = l >> 4;
  const int m0 = by * 256, n0 = bx * 128;
  const int wr = (w >> 1) * 64, wc = (w & 1) * 64;

  const int sr = tid >> 3;
  const int scb = ((tid & 7) * 16) ^ ((sr & 7) << 4);
  const bf16_t* Ab = A + (size_t)m0 * K + (scb >> 1);
  const bf16_t* Bb = Bt + (size_t)n0 * K + (scb >> 1);
  const int nk = K >> 6;

  const int hA = w >> 2;
  const int rA = ((w >> 1) & 1) * 64 + lr;
  const int rB = wc + lr;
  const int xr = (lr & 7) << 4;

  auto STAGE_A = [&](int t, int h) {
    const bf16_t* g = Ab + (size_t)(h * 128 + sr) * K + t * 64;
    char* d = smem + ((size_t)(t & 1) * 2 + h) * 16384 + tid * 16;
    gload16(g, d);
    gload16(g + (size_t)64 * K, d + 8192);
  };
  auto STAGE_B = [&](int t) {
    const bf16_t* g = Bb + (size_t)sr * K + t * 64;
    char* d = smem + 65536 + (size_t)(t & 1) * 16384 + tid * 16;
    gload16(g, d);
    gload16(g + (size_t)64 * K, d + 8192);
  };

  f32x4 acc[4][4] = {};
  bf16x8 af[2][2], bf[4][2];

  STAGE_A(0, 0); STAGE_A(0, 1); STAGE_B(0); STAGE_B(1); STAGE_A(1, 0);
  asm volatile("s_waitcnt vmcnt(4)" ::: "memory");
  GBAR();

  for (int t = 0; t < nk; ++t) {
    const char* pA = smem + ((size_t)(t & 1) * 2 + hA) * 16384;
    const char* pB = smem + 65536 + (size_t)(t & 1) * 16384;
    auto LDA = [&](int mf, int ks) {
      return *(const bf16x8*)(pA + (rA + mf * 16) * 128 + ((ks * 64 + lg * 16) ^ xr));
    };
    auto LDB = [&](int nf, int ks) {
      return *(const bf16x8*)(pB + (rB + nf * 16) * 128 + ((ks * 64 + lg * 16) ^ xr));
    };
    af[0][0] = LDA(0, 0); af[0][1] = LDA(0, 1);
    af[1][0] = LDA(1, 0); af[1][1] = LDA(1, 1);
    bf[0][0] = LDB(0, 0); bf[0][1] = LDB(0, 1);
    bf[1][0] = LDB(1, 0); bf[1][1] = LDB(1, 1);
    if (t + 1 < nk) STAGE_A(t + 1, 1);
    GBAR(); LGKM0();
    __builtin_amdgcn_s_setprio(1);
    MFMA8(0, 0)
    __builtin_amdgcn_s_setprio(0);
    GBAR();
    bf[2][0] = LDB(2, 0); bf[2][1] = LDB(2, 1);
    bf[3][0] = LDB(3, 0); bf[3][1] = LDB(3, 1);
    GBAR(); LGKM0();
    __builtin_amdgcn_s_setprio(1);
    MFMA8(0, 1)
    __builtin_amdgcn_s_setprio(0);
    GBAR();
    af[0][0] = LDA(2, 0); af[0][1] = LDA(2, 1);
    af[1][0] = LDA(3, 0); af[1][1] = LDA(3, 1);
    if (t + 2 < nk) STAGE_B(t + 2);
    GBAR(); LGKM0();
    __builtin_amdgcn_s_setprio(1);
    MFMA8(1, 0)
    __builtin_amdgcn_s_setprio(0);
    GBAR();
    if (t + 2 < nk) STAGE_A(t + 2, 0);
    GBAR();
    __builtin_amdgcn_s_setprio(1);
    MFMA8(1, 1)
    __builtin_amdgcn_s_setprio(0);
    if (t + 2 < nk)      asm volatile("s_waitcnt vmcnt(4)" ::: "memory");
    else if (t + 1 < nk) asm volatile("s_waitcnt vmcnt(0)" ::: "memory");
    GBAR();
  }

#pragma unroll
  for (int mf = 0; mf < 4; ++mf) {
#pragma unroll
    for (int nf = 0; nf < 4; ++nf) {
      int col = n0 + wc + nf * 16 + lr;
      float bb = bias[col];
      int rowb = m0 + wr + mf * 16 + lg * 4;
#pragma unroll
      for (int r = 0; r < 4; ++r) {
        float v = acc[mf][nf][r] + bb;
        Cout[(size_t)(rowb + r) * N + col] = v;
      }
    }
  }
}

__global__ __launch_bounds__(512, 1) void gemm_proj_kernel(
    const bf16_t* __restrict__ A, const bf16_t* __restrict__ Bt,
    const float* __restrict__ bias, float* __restrict__ Cout) {
  extern __shared__ char smem[];
  int bid = blockIdx.x;
  int wg = (bid & 7) * 32 + (bid >> 3);
  gemm8_body(smem, A, Bt, bias, Cout, 1024, 1024, wg % 8, wg / 8);
}

// ---------------------------------------------------------------------------
// Flash attention, block-shared K/V, KVBLK=64. NEW (T15-lite): both sub-tile
// QK^T clusters issued back-to-back (dual sa/sb accumulators) so sub-0's
// softmax VALU overlaps sub-1's in-flight MFMAs, and sub-1's softmax
// overlaps sub-0's PV MFMAs. Same sync structure, same layouts.
// ---------------------------------------------------------------------------
#define STAGE64(bf, it)                                                       \
  {                                                                           \
    gload16(kba + (size_t)(it) * 4096 + tid * 8, &sKV[bf][tid * 16]);         \
    gload16(kba + (size_t)(it) * 4096 + 2048 + tid * 8, &sKV[bf][4096 + tid * 16]); \
    gload16(vba + (size_t)(it) * 4096 + tid * 8, &sKV[bf][8192 + tid * 16]);  \
    gload16(vba + (size_t)(it) * 4096 + 2048 + tid * 8, &sKV[bf][12288 + tid * 16]); \
  }
#define QKT(sub, dst)                                                         \
  {                                                                           \
    bf16x8 kf[4];                                                             \
    _Pragma("unroll") for (int c = 0; c < 4; ++c)                             \
        kf[c] = *(const bf16x8*)&sKV[buf][(sub) * 4096 + c * 1024 + l * 16];  \
    dst = (f32x16){};                                                         \
    __builtin_amdgcn_s_setprio(1);                                            \
    _Pragma("unroll") for (int ks = 0; ks < 4; ++ks)                          \
        dst = __builtin_amdgcn_mfma_f32_32x32x16_bf16(kf[ks], qf[ks], dst, 0, 0, 0); \
    __builtin_amdgcn_s_setprio(0);                                            \
  }
#define SMPV(sub, tcur, src)                                                  \
  {                                                                           \
    bf16x8 vf[4];                                                             \
    _Pragma("unroll") for (int c = 0; c < 4; ++c)                             \
        vf[c] = *(const bf16x8*)&sKV[buf][8192 + (sub) * 4096 + c * 1024 + l * 16]; \
    float sv[16];                                                             \
    const bool mt = is_self && ((tcur) == qw);                                \
    _Pragma("unroll") for (int r = 0; r < 16; ++r) {                          \
      float v = src[r];                                                       \
      if (mt) {                                                               \
        int kvr = (r & 3) + 8 * (r >> 2) + kv4;                               \
        v = (kvr > ql) ? -1e30f : v;                                          \
      }                                                                       \
      sv[r] = v;                                                              \
    }                                                                         \
    float tm = fmaxf(                                                         \
        fmaxf(fmaxf(fmaxf(sv[0], sv[1]), fmaxf(sv[2], sv[3])),                \
              fmaxf(fmaxf(sv[4], sv[5]), fmaxf(sv[6], sv[7]))),               \
        fmaxf(fmaxf(fmaxf(sv[8], sv[9]), fmaxf(sv[10], sv[11])),              \
              fmaxf(fmaxf(sv[12], sv[13]), fmaxf(sv[14], sv[15]))));          \
    tm = xmax32(tm);                                                          \
    if (!__all(tm <= mcur + 64.f)) {                                          \
      float mn = fmaxf(mcur, tm);                                             \
      float sc = FEXP2((mcur - mn) * EXP2C);                                  \
      mcur = mn;                                                              \
      lcur *= sc;                                                             \
      _Pragma("unroll") for (int mb = 0; mb < 2; ++mb)                        \
          _Pragma("unroll") for (int r = 0; r < 16; ++r) oacc[mb][r] *= sc;   \
    }                                                                         \
    const float hm = mcur * EXP2C;                                            \
    float pf[16];                                                             \
    _Pragma("unroll") for (int r = 0; r < 16; ++r)                            \
        pf[r] = FEXP2(__builtin_fmaf(sv[r], EXP2C, -hm));                     \
    float ps = (((pf[0] + pf[1]) + (pf[2] + pf[3])) +                         \
                ((pf[4] + pf[5]) + (pf[6] + pf[7]))) +                        \
               (((pf[8] + pf[9]) + (pf[10] + pf[11])) +                       \
                ((pf[12] + pf[13]) + (pf[14] + pf[15])));                     \
    ps = xsum32(ps);                                                          \
    lcur += ps;                                                               \
    unsigned o01 = pkbf(pf[0], pf[1]), o23 = pkbf(pf[2], pf[3]);              \
    unsigned o45 = pkbf(pf[4], pf[5]), o67 = pkbf(pf[6], pf[7]);              \
    unsigned o89 = pkbf(pf[8], pf[9]), o1011 = pkbf(pf[10], pf[11]);          \
    unsigned o1213 = pkbf(pf[12], pf[13]), o1415 = pkbf(pf[14], pf[15]);      \
    plswap(o01, o45); plswap(o23, o67);                                       \
    plswap(o89, o1213); plswap(o1011, o1415);                                 \
    uint4 w0 = { o01, o23, o45, o67 };                                        \
    uint4 w1 = { o89, o1011, o1213, o1415 };                                  \
    bf16x8 pb0 = __builtin_bit_cast(bf16x8, w0);                              \
    bf16x8 pb1 = __builtin_bit_cast(bf16x8, w1);                              \
    __builtin_amdgcn_s_setprio(1);                                            \
    oacc[0] = __builtin_amdgcn_mfma_f32_32x32x16_bf16(vf[0], pb0, oacc[0], 0, 0, 0); \
    oacc[0] = __builtin_amdgcn_mfma_f32_32x32x16_bf16(vf[1], pb1, oacc[0], 0, 0, 0); \
    oacc[1] = __builtin_amdgcn_mfma_f32_32x32x16_bf16(vf[2], pb0, oacc[1], 0, 0, 0); \
    oacc[1] = __builtin_amdgcn_mfma_f32_32x32x16_bf16(vf[3], pb1, oacc[1], 0, 0, 0); \
    __builtin_amdgcn_s_setprio(0);                                            \
  }

__global__ __launch_bounds__(256) void attn_kernel(
    const bf16_t* __restrict__ qkv,
    const bf16_t* __restrict__ kfs, const bf16_t* __restrict__ vfs,
    const bf16_t* __restrict__ kfc, const bf16_t* __restrict__ vfc,
    bf16_t* __restrict__ obuf) {
  __shared__ __align__(16) char sKV[2][16384];  // 32 KB; epilogue aliases [0]

  const int tid = threadIdx.x;
  const int w = tid >> 6, l = tid & 63;
  const int ql = l & 31;
  const bool uhi = l >= 32;
  const int kv4 = uhi ? 4 : 0;
  const int hi8 = uhi ? 8 : 0;

  const int bid = blockIdx.x;
  const bool is_self = bid < 512;
  int qb, bh, nt32;
  if (is_self) {  // heaviest blocks first
    qb = 7 - (bid >> 6);
    bh = bid & 63;
    nt32 = qb * 4 + 4;
  } else {
    int cb = bid - 512;
    qb = cb >> 6;
    bh = cb & 63;
    nt32 = 8;
  }
  const int qw = qb * 4 + w;
  const int b = bh >> 4, h = bh & 15;
  const int hcol = h * 64;
  const int q0 = qw * 32;
  const int tlim = is_self ? qw : (nt32 - 1);
  const int nit = nt32 >> 1;

  const bf16_t* kba; const bf16_t* vba; int ooff;
  if (is_self) {
    kba = kfs + (size_t)bh * 32 * 2048; vba = vfs + (size_t)bh * 32 * 2048; ooff = 0;
  } else {
    kba = kfc + (size_t)bh * 8 * 2048;  vba = vfc + (size_t)bh * 8 * 2048;  ooff = 1024;
  }

  const bf16_t* qrow = qkv + (size_t)(b * 1024 + q0 + ql) * 3072 + hcol + hi8;
  bf16x8 qf[4];
#pragma unroll
  for (int ks = 0; ks < 4; ++ks) qf[ks] = *(const bf16x8*)(qrow + ks * 16);

  float mcur = -1e30f, lcur = 0.f;
  f32x16 oacc[2] = {};
  f32x16 sa, sb;

  STAGE64(0, 0);
  __syncthreads();
  int buf = 0;
  for (int it = 0; it < nit; ++it) {
    if (it + 1 < nit) STAGE64(buf ^ 1, it + 1);
    const int t0 = 2 * it, t1 = 2 * it + 1;
    const bool d0 = (t0 <= tlim), d1 = (t1 <= tlim);
    // issue both QK^T clusters first (ILP: softmax(0) overlaps QKT(1) MFMAs)
    if (d0) QKT(0, sa);
    if (d1) QKT(1, sb);
    if (d0) SMPV(0, t0, sa);
    if (d1) SMPV(1, t1, sb);
    __syncthreads();
    buf ^= 1;
  }

  // ---- wave-local epilogue: normalize, swizzled transpose, store ----
  const float rl = 1.0f / lcur;
  char* swp = &sKV[0][0] + w * 4096;
#pragma unroll
  for (int mb = 0; mb < 2; ++mb)
#pragma unroll
    for (int r2 = 0; r2 < 8; ++r2) {
      float lo = oacc[mb][2 * r2] * rl;
      float hiv = oacc[mb][2 * r2 + 1] * rl;
      int hdb = (r2 & 1) * 2 + 8 * (r2 >> 1) + kv4 + mb * 32;
      int off = (ql * 128 + hdb * 2) ^ ((ql & 7) << 4);
      *(unsigned*)(swp + off) = pkbf(lo, hiv);
    }
  __syncthreads();
  const int orow = b * 2048 + ooff + q0;
#pragma unroll
  for (int it = 0; it < 4; ++it) {
    int idx = it * 64 + l;
    int q = idx >> 3, ch = idx & 7;
    int off = (q * 128 + ch * 16) ^ ((q & 7) << 4);
    uint4 d = *(uint4*)(swp + off);
    *(uint4*)&obuf[(size_t)(orow + q) * 1024 + hcol + ch * 8] = d;
  }
}

// ---------------------------------------------------------------------------
extern "C" void kernel_launch(void* const* d_in, const int* in_sizes, int n_in,
                              void* d_out, int out_size, void* d_ws, size_t ws_size,
                              hipStream_t stream) {
  (void)in_sizes; (void)n_in; (void)out_size; (void)ws_size;
  const float* x   = (const float*)d_in[0];
  const float* pkg = (const float*)d_in[1];
  const float* Wc  = (const float*)d_in[2];
  const float* bc  = (const float*)d_in[3];
  const float* Wk  = (const float*)d_in[4];
  const float* bk  = (const float*)d_in[5];
  const float* Wp  = (const float*)d_in[6];
  const float* bp  = (const float*)d_in[7];
  float* out = (float*)d_out;

  char* ws = (char*)d_ws;
  const size_t MB = 1u << 20;
  bf16_t* xb   = (bf16_t*)(ws + 0 * MB);   // [4096][1024]   8 MB
  bf16_t* pkb  = (bf16_t*)(ws + 8 * MB);   // [1024][1024]   2 MB
  bf16_t* Wct  = (bf16_t*)(ws + 10 * MB);  // [3072][1024]   6 MB
  bf16_t* Wkt  = (bf16_t*)(ws + 16 * MB);  // [2048][1024]   4 MB
  bf16_t* Wpt  = (bf16_t*)(ws + 20 * MB);  // [1024][1024]   2 MB
  bf16_t* vfs  = (bf16_t*)(ws + 22 * MB);  // packed self V^T frags  8 MB
  bf16_t* kfc  = (bf16_t*)(ws + 30 * MB);  // packed cross K frags   2 MB
  bf16_t* vfc  = (bf16_t*)(ws + 32 * MB);  // packed cross V^T frags 2 MB
  bf16_t* abuf = (bf16_t*)(ws + 34 * MB);  // [8192][1024]  16 MB  (ws total 50 MB)
  bf16_t* qkvb = (bf16_t*)d_out;                      // [4096][3072] 24 MB (Q cols live)
  bf16_t* kfs  = (bf16_t*)((char*)d_out + 24 * MB);   // packed self K frags 8 MB

  // 1: convert inputs + transpose-convert weights (fused)
  prep_kernel<<<11264, 256, 0, stream>>>(x, xb, pkg, pkb, Wc, Wct, Wk, Wkt, Wp, Wpt);
  // 2: qkv + kkv GEMM with fused fragment-pack epilogue
  gemm2_kernel<<<224, 512, 131072, stream>>>(xb, Wct, bc, qkvb, pkb, Wkt, bk,
                                             kfs, vfs, kfc, vfc);
  // 3: attention (KVBLK=64, dual-sa ILP)
  attn_kernel<<<1024, 256, 0, stream>>>(qkvb, kfs, vfs, kfc, vfc, abuf);
  // 4: output projection (8-phase 256x128, 256 blocks = all CUs)
  gemm_proj_kernel<<<256, 512, 98304, stream>>>(abuf, Wpt, bp, out);
}

// Round 23
// 101.690 us; speedup vs baseline: 1.0228x; 1.0228x over previous
//
#include <hip/hip_runtime.h>
#include <hip/hip_bf16.h>

typedef __bf16 bf16_t;
typedef bf16_t bf16x8 __attribute__((ext_vector_type(8)));
typedef bf16_t bf16x4 __attribute__((ext_vector_type(4)));
typedef float f32x4 __attribute__((ext_vector_type(4)));
typedef float f32x16 __attribute__((ext_vector_type(16)));

#define EXP2C 0.1803368867f  // 0.125 * log2(e)
#define FEXP2(x) __builtin_amdgcn_exp2f(x)  // v_exp_f32 (base-2)

// async global->LDS, 16B per lane (dest must be wave-uniform base + lane*16)
__device__ __forceinline__ void gload16(const void* g, void* l) {
  __builtin_amdgcn_global_load_lds(
      (const __attribute__((address_space(1))) void*)g,
      (__attribute__((address_space(3))) void*)l, 16, 0, 0);
}

__device__ __forceinline__ unsigned pkbf(float lo, float hi) {
  unsigned short a = __builtin_bit_cast(unsigned short, (bf16_t)lo);
  unsigned short b = __builtin_bit_cast(unsigned short, (bf16_t)hi);
  return (unsigned)a | ((unsigned)b << 16);
}

// v_permlane32_swap_b32: swaps a.hi(lanes32-63) with b.lo(lanes0-31).
__device__ __forceinline__ void plswap(unsigned& a, unsigned& b) {
#if __has_builtin(__builtin_amdgcn_permlane32_swap)
  auto r = __builtin_amdgcn_permlane32_swap(a, b, false, false);
  a = r[0]; b = r[1];
#else
  asm("v_permlane32_swap_b32 %0, %1" : "+v"(a), "+v"(b));
#endif
}
__device__ __forceinline__ float xmax32(float x) {
  unsigned a = __builtin_bit_cast(unsigned, x), b = a;
  plswap(a, b);
  return fmaxf(__builtin_bit_cast(float, a), __builtin_bit_cast(float, b));
}
__device__ __forceinline__ float xsum32(float x) {
  unsigned a = __builtin_bit_cast(unsigned, x), b = a;
  plswap(a, b);
  return __builtin_bit_cast(float, a) + __builtin_bit_cast(float, b);
}

// ---------------------------------------------------------------------------
// fused prep: cvt x, cvt pred_kg, tcvt Wc/Wk/Wp
// ---------------------------------------------------------------------------
__global__ __launch_bounds__(256) void prep_kernel(
    const float* __restrict__ x, bf16_t* __restrict__ xb,
    const float* __restrict__ pkg, bf16_t* __restrict__ pkb,
    const float* __restrict__ Wc, bf16_t* __restrict__ Wct,
    const float* __restrict__ Wk, bf16_t* __restrict__ Wkt,
    const float* __restrict__ Wp, bf16_t* __restrict__ Wpt) {
  __shared__ float tile[32][33];
  const int bid = blockIdx.x, tid = threadIdx.x;
  if (bid < 5120) {  // vector convert
    int i = bid * 256 + tid;
    const float* src; bf16_t* dst;
    if (i < 1048576) { src = x; dst = xb; }
    else { i -= 1048576; src = pkg; dst = pkb; }
    float4 v = reinterpret_cast<const float4*>(src)[i];
    bf16x4 o = { (bf16_t)v.x, (bf16_t)v.y, (bf16_t)v.z, (bf16_t)v.w };
    reinterpret_cast<bf16x4*>(dst)[i] = o;
    return;
  }
  int r = bid - 5120;
  int xx = r % 192, ky = r / 192;
  const float* W; bf16_t* T; int N;
  if (xx < 96) { W = Wc; T = Wct; N = 3072; }
  else if (xx < 160) { W = Wk; T = Wkt; N = 2048; xx -= 96; }
  else { W = Wp; T = Wpt; N = 1024; xx -= 160; }
  const int K = 1024;
  int tx = tid & 31, ty = tid >> 5;
  int n0 = xx * 32, k0 = ky * 32;
#pragma unroll
  for (int i = 0; i < 4; ++i)
    tile[ty + i * 8][tx] = W[(size_t)(k0 + ty + i * 8) * N + n0 + tx];
  __syncthreads();
#pragma unroll
  for (int i = 0; i < 4; ++i)
    T[(size_t)(n0 + ty + i * 8) * K + k0 + tx] = (bf16_t)tile[tx][ty + i * 8];
}

#define GBAR() __builtin_amdgcn_s_barrier()
#define LGKM0() asm volatile("s_waitcnt lgkmcnt(0)" ::: "memory")

// ---------------------------------------------------------------------------
// 256x256 8-wave GEMM body with fused fragment-pack epilogue (R21-verified).
// ---------------------------------------------------------------------------
__device__ __forceinline__ void gemm256_body(
    char* smem, const bf16_t* __restrict__ A, const bf16_t* __restrict__ Bt,
    const float* __restrict__ bias, bf16_t* __restrict__ Cout, int N,
    int K, int bx, int by, int mode, bf16_t* __restrict__ fdst,
    int NT, int bfb, int h0, int t0) {
  const int tid = threadIdx.x;
  const int l = tid & 63, w = tid >> 6;
  const int lr = l & 15, lg = l >> 4;
  const int m0 = by * 256, n0 = bx * 256;
  const int wr = (w >> 2) * 128, wc = (w & 3) * 64;
  const int hA = w >> 2, hB = (w >> 1) & 1;

  const int sr = tid >> 3;
  const int scb = ((tid & 7) * 16) ^ ((sr & 7) << 4);
  const bf16_t* Ab = A + (size_t)m0 * K + (scb >> 1);
  const bf16_t* Bb = Bt + (size_t)n0 * K + (scb >> 1);
  const int nk = K >> 6;
  const int xr = (lr & 7) << 4;

  auto STAGE_A = [&](int t, int h) {
    const bf16_t* g = Ab + (size_t)(h * 128 + sr) * K + t * 64;
    char* d = smem + ((size_t)(t & 1) * 2 + h) * 16384 + tid * 16;
    gload16(g, d);
    gload16(g + (size_t)64 * K, d + 8192);
  };
  auto STAGE_B = [&](int t, int h) {
    const bf16_t* g = Bb + (size_t)(h * 128 + sr) * K + t * 64;
    char* d = smem + 65536 + ((size_t)(t & 1) * 2 + h) * 16384 + tid * 16;
    gload16(g, d);
    gload16(g + (size_t)64 * K, d + 8192);
  };

  f32x4 acc[8][4] = {};
  bf16x8 af[4][2], bf[2][2][2];

  STAGE_A(0, 0); STAGE_A(0, 1); STAGE_B(0, 0); STAGE_B(0, 1);
  asm volatile("s_waitcnt vmcnt(0)" ::: "memory");
  GBAR();

  for (int t = 0; t < nk; ++t) {
    const char* pA = smem + ((size_t)(t & 1) * 2 + hA) * 16384;
    const char* pB = smem + 65536 + ((size_t)(t & 1) * 2 + hB) * 16384;
    auto LDA = [&](int mf, int ks) {
      return *(const bf16x8*)(pA + (mf * 16 + lr) * 128 + ((ks * 64 + lg * 16) ^ xr));
    };
    auto LDB = [&](int nf, int ks) {
      return *(const bf16x8*)(pB + ((w & 1) * 64 + nf * 16 + lr) * 128 + ((ks * 64 + lg * 16) ^ xr));
    };
#pragma unroll
    for (int mf = 0; mf < 4; ++mf) { af[mf][0] = LDA(mf, 0); af[mf][1] = LDA(mf, 1); }
#pragma unroll
    for (int nf = 0; nf < 2; ++nf) { bf[0][nf][0] = LDB(nf, 0); bf[0][nf][1] = LDB(nf, 1); }
    if (t + 1 < nk) { STAGE_A(t + 1, 0); STAGE_B(t + 1, 0); }
    GBAR(); LGKM0();
    __builtin_amdgcn_s_setprio(1);
#pragma unroll
    for (int mf = 0; mf < 4; ++mf)
#pragma unroll
      for (int nf = 0; nf < 2; ++nf) {
        acc[mf][nf] = __builtin_amdgcn_mfma_f32_16x16x32_bf16(af[mf][0], bf[0][nf][0], acc[mf][nf], 0, 0, 0);
        acc[mf][nf] = __builtin_amdgcn_mfma_f32_16x16x32_bf16(af[mf][1], bf[0][nf][1], acc[mf][nf], 0, 0, 0);
      }
    __builtin_amdgcn_s_setprio(0);
    GBAR();
#pragma unroll
    for (int nf = 0; nf < 2; ++nf) { bf[1][nf][0] = LDB(2 + nf, 0); bf[1][nf][1] = LDB(2 + nf, 1); }
    if (t + 1 < nk) { STAGE_A(t + 1, 1); STAGE_B(t + 1, 1); }
    GBAR(); LGKM0();
    __builtin_amdgcn_s_setprio(1);
#pragma unroll
    for (int mf = 0; mf < 4; ++mf)
#pragma unroll
      for (int nf = 0; nf < 2; ++nf) {
        acc[mf][2 + nf] = __builtin_amdgcn_mfma_f32_16x16x32_bf16(af[mf][0], bf[1][nf][0], acc[mf][2 + nf], 0, 0, 0);
        acc[mf][2 + nf] = __builtin_amdgcn_mfma_f32_16x16x32_bf16(af[mf][1], bf[1][nf][1], acc[mf][2 + nf], 0, 0, 0);
      }
    __builtin_amdgcn_s_setprio(0);
    GBAR();
#pragma unroll
    for (int mf = 0; mf < 4; ++mf) { af[mf][0] = LDA(4 + mf, 0); af[mf][1] = LDA(4 + mf, 1); }
    GBAR(); LGKM0();
    __builtin_amdgcn_s_setprio(1);
#pragma unroll
    for (int mf = 0; mf < 4; ++mf)
#pragma unroll
      for (int nf = 0; nf < 2; ++nf) {
        acc[4 + mf][nf] = __builtin_amdgcn_mfma_f32_16x16x32_bf16(af[mf][0], bf[0][nf][0], acc[4 + mf][nf], 0, 0, 0);
        acc[4 + mf][nf] = __builtin_amdgcn_mfma_f32_16x16x32_bf16(af[mf][1], bf[0][nf][1], acc[4 + mf][nf], 0, 0, 0);
      }
    __builtin_amdgcn_s_setprio(0);
    GBAR();
    __builtin_amdgcn_s_setprio(1);
#pragma unroll
    for (int mf = 0; mf < 4; ++mf)
#pragma unroll
      for (int nf = 0; nf < 2; ++nf) {
        acc[4 + mf][2 + nf] = __builtin_amdgcn_mfma_f32_16x16x32_bf16(af[mf][0], bf[1][nf][0], acc[4 + mf][2 + nf], 0, 0, 0);
        acc[4 + mf][2 + nf] = __builtin_amdgcn_mfma_f32_16x16x32_bf16(af[mf][1], bf[1][nf][1], acc[4 + mf][2 + nf], 0, 0, 0);
      }
    __builtin_amdgcn_s_setprio(0);
    asm volatile("s_waitcnt vmcnt(0)" ::: "memory");
    GBAR();
  }

  if (mode == 0) {  // linear bf16 store
#pragma unroll
    for (int mf = 0; mf < 8; ++mf) {
#pragma unroll
      for (int nf = 0; nf < 4; ++nf) {
        int col = n0 + wc + nf * 16 + lr;
        float bb = bias[col];
        int rowb = m0 + wr + mf * 16 + lg * 4;
#pragma unroll
        for (int r = 0; r < 4; ++r) {
          float v = acc[mf][nf][r] + bb;
          Cout[(size_t)(rowb + r) * N + col] = (bf16_t)v;
        }
      }
    }
    return;
  }

  // ---- fragment epilogue: acc -> swizzled LDS bf16 [256][256] ----
#pragma unroll
  for (int mf = 0; mf < 8; ++mf) {
#pragma unroll
    for (int nf = 0; nf < 4; ++nf) {
      int lcol = wc + nf * 16 + lr;
      float bb = bias[n0 + lcol];
      int rowb = wr + mf * 16 + lg * 4;
#pragma unroll
      for (int r = 0; r < 4; ++r) {
        int lrow = rowb + r;
        *(bf16_t*)(smem + lrow * 512 + ((lcol * 2) ^ ((lrow & 7) << 4))) =
            (bf16_t)(acc[mf][nf][r] + bb);
      }
    }
  }
  __syncthreads();
  if (mode == 1) {
#pragma unroll
    for (int i = 0; i < 16; ++i) {
      int g = i * 512 + tid;
      int sub = g >> 8, c = g & 255;
      int ks = c >> 6, l2 = c & 63;
      int tt = sub >> 2, hc = sub & 3;
      int lrow = tt * 32 + (l2 & 31);
      int lcol = hc * 64 + ks * 16 + ((l2 >> 5) * 8);
      uint4 d = *(uint4*)(smem + lrow * 512 + ((lcol * 2) ^ ((lrow & 7) << 4)));
      size_t obase = ((size_t)(bfb + h0 + hc) * NT + (t0 + tt)) * 2048;
      *(uint4*)&fdst[obase + ks * 512 + (size_t)l2 * 8] = d;
    }
  } else {
#pragma unroll
    for (int i = 0; i < 16; ++i) {
      int g = i * 512 + tid;
      int sub = g >> 8, c = g & 255;
      int dd = c >> 6, l2 = c & 63;
      int mb = dd >> 1, ks = dd & 1;
      int tt = sub >> 2, hc = sub & 3;
      int kvr = ks * 16 + ((l2 >> 5) * 8);
      int lcolv = hc * 64 + mb * 32 + (l2 & 31);
      bf16_t tmp[8];
#pragma unroll
      for (int j = 0; j < 8; ++j) {
        int lrow = tt * 32 + kvr + j;
        tmp[j] = *(bf16_t*)(smem + lrow * 512 + ((lcolv * 2) ^ ((lrow & 7) << 4)));
      }
      size_t obase = ((size_t)(bfb + h0 + hc) * NT + (t0 + tt)) * 2048;
      *(bf16x8*)&fdst[obase + dd * 512 + (size_t)l2 * 8] = *(bf16x8*)tmp;
    }
  }
}

__global__ __launch_bounds__(512, 1) void gemm2_kernel(
    const bf16_t* __restrict__ A0, const bf16_t* __restrict__ B0,
    const float* __restrict__ bi0, bf16_t* __restrict__ C0,
    const bf16_t* __restrict__ A1, const bf16_t* __restrict__ B1,
    const float* __restrict__ bi1,
    bf16_t* __restrict__ kfs, bf16_t* __restrict__ vfs,
    bf16_t* __restrict__ kfc, bf16_t* __restrict__ vfc) {
  extern __shared__ char smem[];
  int bid = blockIdx.x;
  int wg = (bid & 7) * 28 + (bid >> 3);
  if (wg < 192) {
    int bx = wg % 12, by = wg / 12;
    int b = by >> 2, t0 = (by & 3) * 8;
    if (bx < 4)
      gemm256_body(smem, A0, B0, bi0, C0, 3072, 1024, bx, by, 0, nullptr, 0, 0, 0, 0);
    else if (bx < 8)
      gemm256_body(smem, A0, B0, bi0, nullptr, 3072, 1024, bx, by, 1, kfs, 32, b * 16, (bx - 4) * 4, t0);
    else
      gemm256_body(smem, A0, B0, bi0, nullptr, 3072, 1024, bx, by, 2, vfs, 32, b * 16, (bx - 8) * 4, t0);
  } else {
    int r = wg - 192;
    int bx = r % 8, by = r / 8;
    if (bx < 4)
      gemm256_body(smem, A1, B1, bi1, nullptr, 2048, 1024, bx, by, 1, kfc, 8, by * 16, bx * 4, 0);
    else
      gemm256_body(smem, A1, B1, bi1, nullptr, 2048, 1024, bx, by, 2, vfc, 8, by * 16, (bx - 4) * 4, 0);
  }
}

// ---------------------------------------------------------------------------
// 8-phase GEMM body 256x128 (R15-verified) — proj (256 blocks = all CUs)
// ---------------------------------------------------------------------------
#define MFMA2(mi, ni)                                                         \
  acc[mi][ni] = __builtin_amdgcn_mfma_f32_16x16x32_bf16(af[(mi) & 1][0], bf[ni][0], acc[mi][ni], 0, 0, 0); \
  acc[mi][ni] = __builtin_amdgcn_mfma_f32_16x16x32_bf16(af[(mi) & 1][1], bf[ni][1], acc[mi][ni], 0, 0, 0);
#define MFMA8(qm, qn)                                                         \
  MFMA2(2 * (qm) + 0, 2 * (qn) + 0) MFMA2(2 * (qm) + 0, 2 * (qn) + 1)         \
  MFMA2(2 * (qm) + 1, 2 * (qn) + 0) MFMA2(2 * (qm) + 1, 2 * (qn) + 1)

__device__ __forceinline__ void gemm8_body(
    char* smem, const bf16_t* __restrict__ A, const bf16_t* __restrict__ Bt,
    const float* __restrict__ bias, float* __restrict__ Cout,
    int N, int K, int bx, int by) {
  const int tid = threadIdx.x;
  const int l = tid & 63, w = tid >> 6;
  const int lr = l & 15, lg = l >> 4;
  const int m0 = by * 256, n0 = bx * 128;
  const int wr = (w >> 1) * 64, wc = (w & 1) * 64;

  const int sr = tid >> 3;
  const int scb = ((tid & 7) * 16) ^ ((sr & 7) << 4);
  const bf16_t* Ab = A + (size_t)m0 * K + (scb >> 1);
  const bf16_t* Bb = Bt + (size_t)n0 * K + (scb >> 1);
  const int nk = K >> 6;

  const int hA = w >> 2;
  const int rA = ((w >> 1) & 1) * 64 + lr;
  const int rB = wc + lr;
  const int xr = (lr & 7) << 4;

  auto STAGE_A = [&](int t, int h) {
    const bf16_t* g = Ab + (size_t)(h * 128 + sr) * K + t * 64;
    char* d = smem + ((size_t)(t & 1) * 2 + h) * 16384 + tid * 16;
    gload16(g, d);
    gload16(g + (size_t)64 * K, d + 8192);
  };
  auto STAGE_B = [&](int t) {
    const bf16_t* g = Bb + (size_t)sr * K + t * 64;
    char* d = smem + 65536 + (size_t)(t & 1) * 16384 + tid * 16;
    gload16(g, d);
    gload16(g + (size_t)64 * K, d + 8192);
  };

  f32x4 acc[4][4] = {};
  bf16x8 af[2][2], bf[4][2];

  STAGE_A(0, 0); STAGE_A(0, 1); STAGE_B(0); STAGE_B(1); STAGE_A(1, 0);
  asm volatile("s_waitcnt vmcnt(4)" ::: "memory");
  GBAR();

  for (int t = 0; t < nk; ++t) {
    const char* pA = smem + ((size_t)(t & 1) * 2 + hA) * 16384;
    const char* pB = smem + 65536 + (size_t)(t & 1) * 16384;
    auto LDA = [&](int mf, int ks) {
      return *(const bf16x8*)(pA + (rA + mf * 16) * 128 + ((ks * 64 + lg * 16) ^ xr));
    };
    auto LDB = [&](int nf, int ks) {
      return *(const bf16x8*)(pB + (rB + nf * 16) * 128 + ((ks * 64 + lg * 16) ^ xr));
    };
    af[0][0] = LDA(0, 0); af[0][1] = LDA(0, 1);
    af[1][0] = LDA(1, 0); af[1][1] = LDA(1, 1);
    bf[0][0] = LDB(0, 0); bf[0][1] = LDB(0, 1);
    bf[1][0] = LDB(1, 0); bf[1][1] = LDB(1, 1);
    if (t + 1 < nk) STAGE_A(t + 1, 1);
    GBAR(); LGKM0();
    __builtin_amdgcn_s_setprio(1);
    MFMA8(0, 0)
    __builtin_amdgcn_s_setprio(0);
    GBAR();
    bf[2][0] = LDB(2, 0); bf[2][1] = LDB(2, 1);
    bf[3][0] = LDB(3, 0); bf[3][1] = LDB(3, 1);
    GBAR(); LGKM0();
    __builtin_amdgcn_s_setprio(1);
    MFMA8(0, 1)
    __builtin_amdgcn_s_setprio(0);
    GBAR();
    af[0][0] = LDA(2, 0); af[0][1] = LDA(2, 1);
    af[1][0] = LDA(3, 0); af[1][1] = LDA(3, 1);
    if (t + 2 < nk) STAGE_B(t + 2);
    GBAR(); LGKM0();
    __builtin_amdgcn_s_setprio(1);
    MFMA8(1, 0)
    __builtin_amdgcn_s_setprio(0);
    GBAR();
    if (t + 2 < nk) STAGE_A(t + 2, 0);
    GBAR();
    __builtin_amdgcn_s_setprio(1);
    MFMA8(1, 1)
    __builtin_amdgcn_s_setprio(0);
    if (t + 2 < nk)      asm volatile("s_waitcnt vmcnt(4)" ::: "memory");
    else if (t + 1 < nk) asm volatile("s_waitcnt vmcnt(0)" ::: "memory");
    GBAR();
  }

#pragma unroll
  for (int mf = 0; mf < 4; ++mf) {
#pragma unroll
    for (int nf = 0; nf < 4; ++nf) {
      int col = n0 + wc + nf * 16 + lr;
      float bb = bias[col];
      int rowb = m0 + wr + mf * 16 + lg * 4;
#pragma unroll
      for (int r = 0; r < 4; ++r) {
        float v = acc[mf][nf][r] + bb;
        Cout[(size_t)(rowb + r) * N + col] = v;
      }
    }
  }
}

__global__ __launch_bounds__(512, 1) void gemm_proj_kernel(
    const bf16_t* __restrict__ A, const bf16_t* __restrict__ Bt,
    const float* __restrict__ bias, float* __restrict__ Cout) {
  extern __shared__ char smem[];
  int bid = blockIdx.x;
  int wg = (bid & 7) * 32 + (bid >> 3);
  gemm8_body(smem, A, Bt, bias, Cout, 1024, 1024, wg % 8, wg / 8);
}

// ---------------------------------------------------------------------------
// Flash attention, block-shared K/V, KVBLK=64 per stage (R18/R21-verified).
// ---------------------------------------------------------------------------
#define STAGE64(bf, it)                                                       \
  {                                                                           \
    gload16(kba + (size_t)(it) * 4096 + tid * 8, &sKV[bf][tid * 16]);         \
    gload16(kba + (size_t)(it) * 4096 + 2048 + tid * 8, &sKV[bf][4096 + tid * 16]); \
    gload16(vba + (size_t)(it) * 4096 + tid * 8, &sKV[bf][8192 + tid * 16]);  \
    gload16(vba + (size_t)(it) * 4096 + 2048 + tid * 8, &sKV[bf][12288 + tid * 16]); \
  }
#define QKT(sub)                                                              \
  {                                                                           \
    _Pragma("unroll") for (int c = 0; c < 4; ++c)                             \
        kf[c] = *(const bf16x8*)&sKV[buf][(sub) * 4096 + c * 1024 + l * 16];  \
    sa = (f32x16){};                                                          \
    __builtin_amdgcn_s_setprio(1);                                            \
    _Pragma("unroll") for (int ks = 0; ks < 4; ++ks)                          \
        sa = __builtin_amdgcn_mfma_f32_32x32x16_bf16(kf[ks], qf[ks], sa, 0, 0, 0); \
    __builtin_amdgcn_s_setprio(0);                                            \
  }
#define SMPV(sub, tcur)                                                       \
  {                                                                           \
    _Pragma("unroll") for (int c = 0; c < 4; ++c)                             \
        vf[c] = *(const bf16x8*)&sKV[buf][8192 + (sub) * 4096 + c * 1024 + l * 16]; \
    float sv[16];                                                             \
    const bool mt = is_self && ((tcur) == qw);                                \
    _Pragma("unroll") for (int r = 0; r < 16; ++r) {                          \
      float v = sa[r];                                                        \
      if (mt) {                                                               \
        int kvr = (r & 3) + 8 * (r >> 2) + kv4;                               \
        v = (kvr > ql) ? -1e30f : v;                                          \
      }                                                                       \
      sv[r] = v;                                                              \
    }                                                                         \
    float tm = fmaxf(                                                         \
        fmaxf(fmaxf(fmaxf(sv[0], sv[1]), fmaxf(sv[2], sv[3])),                \
              fmaxf(fmaxf(sv[4], sv[5]), fmaxf(sv[6], sv[7]))),               \
        fmaxf(fmaxf(fmaxf(sv[8], sv[9]), fmaxf(sv[10], sv[11])),              \
              fmaxf(fmaxf(sv[12], sv[13]), fmaxf(sv[14], sv[15]))));          \
    tm = xmax32(tm);                                                          \
    if (!__all(tm <= mcur + 64.f)) {                                          \
      float mn = fmaxf(mcur, tm);                                             \
      float sc = FEXP2((mcur - mn) * EXP2C);                                  \
      mcur = mn;                                                              \
      lcur *= sc;                                                             \
      _Pragma("unroll") for (int mb = 0; mb < 2; ++mb)                        \
          _Pragma("unroll") for (int r = 0; r < 16; ++r) oacc[mb][r] *= sc;   \
    }                                                                         \
    const float hm = mcur * EXP2C;                                            \
    float pf[16];                                                             \
    _Pragma("unroll") for (int r = 0; r < 16; ++r)                            \
        pf[r] = FEXP2(__builtin_fmaf(sv[r], EXP2C, -hm));                     \
    float ps = (((pf[0] + pf[1]) + (pf[2] + pf[3])) +                         \
                ((pf[4] + pf[5]) + (pf[6] + pf[7]))) +                        \
               (((pf[8] + pf[9]) + (pf[10] + pf[11])) +                       \
                ((pf[12] + pf[13]) + (pf[14] + pf[15])));                     \
    ps = xsum32(ps);                                                          \
    lcur += ps;                                                               \
    unsigned o01 = pkbf(pf[0], pf[1]), o23 = pkbf(pf[2], pf[3]);              \
    unsigned o45 = pkbf(pf[4], pf[5]), o67 = pkbf(pf[6], pf[7]);              \
    unsigned o89 = pkbf(pf[8], pf[9]), o1011 = pkbf(pf[10], pf[11]);          \
    unsigned o1213 = pkbf(pf[12], pf[13]), o1415 = pkbf(pf[14], pf[15]);      \
    plswap(o01, o45); plswap(o23, o67);                                       \
    plswap(o89, o1213); plswap(o1011, o1415);                                 \
    uint4 w0 = { o01, o23, o45, o67 };                                        \
    uint4 w1 = { o89, o1011, o1213, o1415 };                                  \
    bf16x8 pb0 = __builtin_bit_cast(bf16x8, w0);                              \
    bf16x8 pb1 = __builtin_bit_cast(bf16x8, w1);                              \
    __builtin_amdgcn_s_setprio(1);                                            \
    oacc[0] = __builtin_amdgcn_mfma_f32_32x32x16_bf16(vf[0], pb0, oacc[0], 0, 0, 0); \
    oacc[0] = __builtin_amdgcn_mfma_f32_32x32x16_bf16(vf[1], pb1, oacc[0], 0, 0, 0); \
    oacc[1] = __builtin_amdgcn_mfma_f32_32x32x16_bf16(vf[2], pb0, oacc[1], 0, 0, 0); \
    oacc[1] = __builtin_amdgcn_mfma_f32_32x32x16_bf16(vf[3], pb1, oacc[1], 0, 0, 0); \
    __builtin_amdgcn_s_setprio(0);                                            \
  }

__global__ __launch_bounds__(256) void attn_kernel(
    const bf16_t* __restrict__ qkv,
    const bf16_t* __restrict__ kfs, const bf16_t* __restrict__ vfs,
    const bf16_t* __restrict__ kfc, const bf16_t* __restrict__ vfc,
    bf16_t* __restrict__ obuf) {
  __shared__ __align__(16) char sKV[2][16384];  // 32 KB; epilogue aliases [0]

  const int tid = threadIdx.x;
  const int w = tid >> 6, l = tid & 63;
  const int ql = l & 31;
  const bool uhi = l >= 32;
  const int kv4 = uhi ? 4 : 0;
  const int hi8 = uhi ? 8 : 0;

  const int bid = blockIdx.x;
  const bool is_self = bid < 512;
  int qb, bh, nt32;
  if (is_self) {  // heaviest blocks first
    qb = 7 - (bid >> 6);
    bh = bid & 63;
    nt32 = qb * 4 + 4;
  } else {
    int cb = bid - 512;
    qb = cb >> 6;
    bh = cb & 63;
    nt32 = 8;
  }
  const int qw = qb * 4 + w;
  const int b = bh >> 4, h = bh & 15;
  const int hcol = h * 64;
  const int q0 = qw * 32;
  const int tlim = is_self ? qw : (nt32 - 1);
  const int nit = nt32 >> 1;

  const bf16_t* kba; const bf16_t* vba; int ooff;
  if (is_self) {
    kba = kfs + (size_t)bh * 32 * 2048; vba = vfs + (size_t)bh * 32 * 2048; ooff = 0;
  } else {
    kba = kfc + (size_t)bh * 8 * 2048;  vba = vfc + (size_t)bh * 8 * 2048;  ooff = 1024;
  }

  const bf16_t* qrow = qkv + (size_t)(b * 1024 + q0 + ql) * 3072 + hcol + hi8;
  bf16x8 qf[4];
#pragma unroll
  for (int ks = 0; ks < 4; ++ks) qf[ks] = *(const bf16x8*)(qrow + ks * 16);

  float mcur = -1e30f, lcur = 0.f;
  f32x16 oacc[2] = {};
  f32x16 sa;
  bf16x8 kf[4], vf[4];

  STAGE64(0, 0);
  __syncthreads();
  int buf = 0;
  for (int it = 0; it < nit; ++it) {
    if (it + 1 < nit) STAGE64(buf ^ 1, it + 1);
    const int t0 = 2 * it, t1 = 2 * it + 1;
    if (t0 <= tlim) {
      QKT(0);
      SMPV(0, t0);
    }
    if (t1 <= tlim) {
      QKT(1);
      SMPV(1, t1);
    }
    __syncthreads();
    buf ^= 1;
  }

  // ---- wave-local epilogue: normalize, swizzled transpose, store ----
  const float rl = 1.0f / lcur;
  char* swp = &sKV[0][0] + w * 4096;
#pragma unroll
  for (int mb = 0; mb < 2; ++mb)
#pragma unroll
    for (int r2 = 0; r2 < 8; ++r2) {
      float lo = oacc[mb][2 * r2] * rl;
      float hiv = oacc[mb][2 * r2 + 1] * rl;
      int hdb = (r2 & 1) * 2 + 8 * (r2 >> 1) + kv4 + mb * 32;
      int off = (ql * 128 + hdb * 2) ^ ((ql & 7) << 4);
      *(unsigned*)(swp + off) = pkbf(lo, hiv);
    }
  __syncthreads();
  const int orow = b * 2048 + ooff + q0;
#pragma unroll
  for (int it = 0; it < 4; ++it) {
    int idx = it * 64 + l;
    int q = idx >> 3, ch = idx & 7;
    int off = (q * 128 + ch * 16) ^ ((q & 7) << 4);
    uint4 d = *(uint4*)(swp + off);
    *(uint4*)&obuf[(size_t)(orow + q) * 1024 + hcol + ch * 8] = d;
  }
}

// ---------------------------------------------------------------------------
extern "C" void kernel_launch(void* const* d_in, const int* in_sizes, int n_in,
                              void* d_out, int out_size, void* d_ws, size_t ws_size,
                              hipStream_t stream) {
  (void)in_sizes; (void)n_in; (void)out_size; (void)ws_size;
  const float* x   = (const float*)d_in[0];
  const float* pkg = (const float*)d_in[1];
  const float* Wc  = (const float*)d_in[2];
  const float* bc  = (const float*)d_in[3];
  const float* Wk  = (const float*)d_in[4];
  const float* bk  = (const float*)d_in[5];
  const float* Wp  = (const float*)d_in[6];
  const float* bp  = (const float*)d_in[7];
  float* out = (float*)d_out;

  char* ws = (char*)d_ws;
  const size_t MB = 1u << 20;
  bf16_t* xb   = (bf16_t*)(ws + 0 * MB);   // [4096][1024]   8 MB
  bf16_t* pkb  = (bf16_t*)(ws + 8 * MB);   // [1024][1024]   2 MB
  bf16_t* Wct  = (bf16_t*)(ws + 10 * MB);  // [3072][1024]   6 MB
  bf16_t* Wkt  = (bf16_t*)(ws + 16 * MB);  // [2048][1024]   4 MB
  bf16_t* Wpt  = (bf16_t*)(ws + 20 * MB);  // [1024][1024]   2 MB
  bf16_t* vfs  = (bf16_t*)(ws + 22 * MB);  // packed self V^T frags  8 MB
  bf16_t* kfc  = (bf16_t*)(ws + 30 * MB);  // packed cross K frags   2 MB
  bf16_t* vfc  = (bf16_t*)(ws + 32 * MB);  // packed cross V^T frags 2 MB
  bf16_t* abuf = (bf16_t*)(ws + 34 * MB);  // [8192][1024]  16 MB  (ws total 50 MB)
  bf16_t* qkvb = (bf16_t*)d_out;                      // [4096][3072] 24 MB (Q cols live)
  bf16_t* kfs  = (bf16_t*)((char*)d_out + 24 * MB);   // packed self K frags 8 MB

  // 1: convert inputs + transpose-convert weights (fused)
  prep_kernel<<<11264, 256, 0, stream>>>(x, xb, pkg, pkb, Wc, Wct, Wk, Wkt, Wp, Wpt);
  // 2: qkv + kkv GEMM with fused fragment-pack epilogue
  gemm2_kernel<<<224, 512, 131072, stream>>>(xb, Wct, bc, qkvb, pkb, Wkt, bk,
                                             kfs, vfs, kfc, vfc);
  // 3: attention (KVBLK=64, 2-buffer pipeline)
  attn_kernel<<<1024, 256, 0, stream>>>(qkvb, kfs, vfs, kfc, vfc, abuf);
  // 4: output projection (8-phase 256x128, 256 blocks = all CUs)
  gemm_proj_kernel<<<256, 512, 98304, stream>>>(abuf, Wpt, bp, out);
}